// Round 10
// baseline (711.537 us; speedup 1.0000x reference)
//
#include <hip/hip_runtime.h>
#include <stdint.h>

#define RELS 8
#define F 256
#define KDIM 2304        // 8*256 stacked relations + 256 root/self columns
#define NKT 36           // KDIM / 64 k-tiles
#define TSZ 8192         // shorts per Wt (tile,kt) chunk: 128 rows x 64 cols
#define SCAN_CHUNK 1024  // bins per scan1 block (256 threads x 4)

// CSR bin order is RELATION-MAJOR: bin = rel*N + dst. For a fixed relation,
// the edges of any contiguous dst-row range are CONTIGUOUS in ssrc2 -> the
// fused kernel's gather is a sequential stream.
// Round-9 verified spill-free recipe (FROZEN): all gather-bank register
// writes unconditional with CLAMPED indices; validity applied only at PROC
// via wave-uniform scalar compare. Round 10 adds: 512-thr blocks (8 waves,
// 16 waves/CU vs 6.4), 8 rows/wave/relation, and cross-relation pk-prefetch
// (next relation's packed-id loads issued before the MFMA phase so their
// latency hides under MFMA + barrier).
// ssrc2 entry: src_id (bits 0..19) | (dst & 63) << 20.
//
// Wt global layout: tiled + FRAGMENT-MAJOR (round-4 verified). chunk(tile,kt)
// is contiguous 16KB holding rows [0,128) x k-units [0,8) (unit = 8 shorts):
//   frag = (row>>6)*8 + ((row>>4)&3)*2 + (unit>>2)
//   lane = (unit&3)*16 + (row&15)
//   addr = chunk_base + frag*512 + lane*8 + (k&7)       // shorts
// k_fused's 64-row LDS A-slice uses the same mapping (row>>6 = 0) with the
// round-6-verified dl-group XOR swizzle on write and read.

typedef __attribute__((ext_vector_type(8))) short short8;
typedef __attribute__((ext_vector_type(4))) float f32x4;
typedef __attribute__((ext_vector_type(2))) unsigned int uint2v;

__device__ __forceinline__ unsigned short f2bf(float f) {
  union { float f; unsigned int u; } v; v.f = f;
  unsigned int u = v.u;
  if ((u & 0x7f800000u) == 0x7f800000u) return (unsigned short)(u >> 16);
  return (unsigned short)((u + 0x7fffu + ((u >> 16) & 1u)) >> 16);  // RNE
}
__device__ __forceinline__ float bf2f(unsigned short b) {
  union { unsigned int u; float f; } v; v.u = ((unsigned int)b) << 16; return v.f;
}

// ---- x fp32 -> compact bf16 [N,256] (small L3-resident gather source)
__global__ void k_xb(const float* __restrict__ x, unsigned short* __restrict__ xb, int N) {
  int tid = blockIdx.x * blockDim.x + threadIdx.x;
  int n = tid >> 6, q = tid & 63;
  if (n >= N) return;
  const float4 v = *(const float4*)&x[(size_t)n * F + q * 4];
  ushort4 o;
  o.x = f2bf(v.x); o.y = f2bf(v.y); o.z = f2bf(v.z); o.w = f2bf(v.w);
  *(ushort4*)&xb[(size_t)n * F + q * 4] = o;
}

// ---- weight convert+transpose into tiled+fragment-major layout ----
// Wt content: row n (output col), k<2048: W[k][n]; else root[k-2048][n].
__global__ void k_wt(const float* __restrict__ W, const float* __restrict__ root,
                     unsigned short* __restrict__ Wt, int Ncols) {
  int tid = blockIdx.x * blockDim.x + threadIdx.x;
  int total = Ncols * KDIM;
  if (tid >= total) return;
  int n = tid / KDIM, k = tid - n * KDIM;
  float v = (k < 2048) ? W[(size_t)k * Ncols + n] : root[(size_t)(k - 2048) * Ncols + n];
  int tile = n >> 7, row = n & 127;
  int kt = k >> 6, c = k & 63;
  int u = c >> 3, w = c & 7;
  int frag = ((row >> 6) << 3) + (((row >> 4) & 3) << 1) + (u >> 2);
  int dl = ((u & 3) << 4) + (row & 15);
  Wt[(size_t)(tile * NKT + kt) * TSZ + frag * 512 + dl * 8 + w] = f2bf(v);
}

// ---- CSR build (relation-major bins) ----
__global__ void k_count(const int* __restrict__ ei, const int* __restrict__ et,
                        int* __restrict__ cnt, int E, int N) {
  int e = blockIdx.x * blockDim.x + threadIdx.x;
  if (e >= E) return;
  int bin = et[e] * N + ei[E + e];
  atomicAdd(&cnt[bin], 1);
}

__global__ void k_scan1(const int* __restrict__ cnt, int* __restrict__ start,
                        int* __restrict__ bsum, int nb) {
  __shared__ int tsum[256];
  const int t = threadIdx.x;
  const int idx = blockIdx.x * SCAN_CHUNK + t * 4;
  int v[4]; int s = 0;
#pragma unroll
  for (int i = 0; i < 4; i++) { v[i] = (idx + i < nb) ? cnt[idx + i] : 0; s += v[i]; }
  tsum[t] = s;
  __syncthreads();
  for (int d = 1; d < 256; d <<= 1) {
    int a = (t >= d) ? tsum[t - d] : 0;
    __syncthreads();
    tsum[t] += a;
    __syncthreads();
  }
  int ex = (t > 0) ? tsum[t - 1] : 0;
#pragma unroll
  for (int i = 0; i < 4; i++) { if (idx + i < nb) start[idx + i] = ex; ex += v[i]; }
  if (t == 255) bsum[blockIdx.x] = tsum[255];
}

__global__ void k_scan2(int* __restrict__ bsum, int nblocks) {
  __shared__ int sh[1024];
  const int t = threadIdx.x;
  sh[t] = (t < nblocks) ? bsum[t] : 0;
  __syncthreads();
  for (int d = 1; d < 1024; d <<= 1) {
    int a = (t >= d) ? sh[t - d] : 0;
    __syncthreads();
    sh[t] += a;
    __syncthreads();
  }
  if (t < nblocks) bsum[t] = (t > 0) ? sh[t - 1] : 0;
  if (t == 1023) bsum[nblocks] = sh[1023];
}

__global__ void k_scan3(int* __restrict__ start, const int* __restrict__ bsum,
                        int nb, int nblocks) {
  int i = blockIdx.x * blockDim.x + threadIdx.x;
  if (i < nb) start[i] += bsum[i >> 10];
  if (i == 0) start[nb] = bsum[nblocks];
}

__global__ void k_scatter(const int* __restrict__ ei, const int* __restrict__ et,
                          const int* __restrict__ start, int* __restrict__ cur,
                          unsigned int* __restrict__ ssrc2, int E, int N) {
  int e = blockIdx.x * blockDim.x + threadIdx.x;
  if (e >= E) return;
  int dst = ei[E + e];
  int bin = et[e] * N + dst;
  int p = atomicAdd(&cur[bin], 1);
  ssrc2[start[bin] + p] = (unsigned)ei[e] | ((unsigned)(dst & 63) << 20);
}

// ---- FUSED per-tile kernel: streaming aggregate -> LDS slice -> MFMA ----
// 8 waves x 8 rows/relation; relation-major bins make each wave's edges ONE
// contiguous ssrc2 range (mean ~16 edges), streamed via the round-9 2-bank
// double buffer (all register writes unconditional, clamped indices). pk
// banks for relation r+1 are prefetched before the MFMA phase of r so only
// the feature-load latency is exposed in phase 1. Zero-init is a per-owned-
// row zero-flush (no shared-frag race, no extra barrier). Accumulator spans
// all 9 relation slices; per-bin edge order == rounds 0-9.
template<int NI, bool RELU, bool OUTBF16>
__global__ __launch_bounds__(512, 2) void k_fused(
    const unsigned short* __restrict__ src, const unsigned short* __restrict__ Wt,
    const int* __restrict__ start, const unsigned int* __restrict__ ssrc2,
    const float* __restrict__ bias, void* __restrict__ outp, int Nn) {
  __shared__ unsigned short slice[4 * 4096];   // 32 KB: [chunk][frag<8][512]
  const int t = threadIdx.x;
  const int lane = t & 63, wid = t >> 6;       // 8 waves, 8 rows each
  const int m0 = blockIdx.x * 64;
  const int c15 = lane & 15, quad = lane >> 4;
  const int wn = wid * (NI * 16);              // wave's output column base
  // gather constants: lane covers feature cols [4*lane, 4*lane+4)
  const int gc = lane >> 4;                    // k-chunk within slice
  const int gL = lane & 15;
  const int gFragLo = gL >> 3;
  const int gDlHi = ((gL >> 1) & 3) << 4;
  const int gW = (gL & 1) * 4;
  const int gSwz = ((gL >> 1) & 3) << 4;       // XOR key (shorts)

  f32x4 acc[4][NI];
#pragma unroll
  for (int i = 0; i < 4; i++)
#pragma unroll
    for (int j = 0; j < NI; j++) acc[i][j] = (f32x4)0.f;

  const unsigned short* Bt = Wt + (size_t)(wn >> 7) * NKT * TSZ + lane * 8;
  const int roff = (lane << 3) ^ ((lane >> 4 & 3) << 4);  // swizzled frag read

// unconditional, index-clamped loads: every register written on every path.
#define LDPK8(P_, eo_)                                                       \
  { _Pragma("unroll") for (int j = 0; j < 8; j++) {                          \
      int i_ = (eo_) + j; P_[j] = ssrc2[i_ < eEm1 ? i_ : eEm1]; } }
#define LDFV8(Fv_, P_)                                                       \
  { _Pragma("unroll") for (int j = 0; j < 8; j++)                            \
      Fv_[j] = *(const ushort4*)&src[(size_t)(P_[j] & 0xFFFFFu) * F + lane * 4]; }
#define FLUSHROW()                                                           \
  {                                                                          \
    float s_ = 1.0f / (float)(cnt > 1 ? cnt : 1);                            \
    int frag_ = (((curDl >> 4) & 3) << 1) | gFragLo;                         \
    int dloc_ = gDlHi | (curDl & 15);                                        \
    uint2v o_;                                                               \
    o_.x = (unsigned)f2bf(accR.x * s_) | ((unsigned)f2bf(accR.y * s_) << 16);\
    o_.y = (unsigned)f2bf(accR.z * s_) | ((unsigned)f2bf(accR.w * s_) << 16);\
    *(uint2v*)&slice[gc * 4096 + frag_ * 512 + (((dloc_ << 3) | gW) ^ gSwz)] = o_; \
  }
#define PROC(pk_, fv_)                                                       \
  {                                                                          \
    int dl_ = (int)((pk_) >> 20);                                            \
    if (dl_ != curDl) {                                                      \
      if (curDl >= 0) FLUSHROW();                                            \
      curDl = dl_; cnt = 0;                                                  \
      accR.x = 0.f; accR.y = 0.f; accR.z = 0.f; accR.w = 0.f;                \
    }                                                                        \
    accR.x += bf2f((fv_).x); accR.y += bf2f((fv_).y);                        \
    accR.z += bf2f((fv_).z); accR.w += bf2f((fv_).w);                        \
    cnt++;                                                                   \
  }
#define PROC8(P_, Fv_, base_)                                                \
  { _Pragma("unroll") for (int j = 0; j < 8; j++)                            \
      if ((base_) + j < eE) PROC(P_[j], Fv_[j]); }
#define BOUNDS(r_)                                                           \
  {                                                                          \
    int rA_ = m0 + wid * 8;                                                  \
    int rB_ = rA_ + 8;                                                       \
    rA_ = rA_ < Nn ? rA_ : Nn;                                               \
    rB_ = rB_ < Nn ? rB_ : Nn;                                               \
    e = start[(r_) * Nn + rA_];                                              \
    eE = start[(r_) * Nn + rB_];                                             \
    eEm1 = (eE > e) ? eE - 1 : 0;                                            \
  }

  int e, eE, eEm1;
  unsigned pkA[8], pkB[8];
  BOUNDS(0);
  LDPK8(pkA, e); LDPK8(pkB, e + 8);    // relation-0 id prologue in flight

  for (int r = 0; r < 9; r++) {
    // ---- phase 1: build fragment-major A-slice for relation r in LDS ----
    if (r < 8) {
      // zero-flush this wave's 8 owned rows (each cell written only by us)
#pragma unroll
      for (int bi = 0; bi < 8; bi++) {
        int row = wid * 8 + bi;
        int frag = (((row >> 4) & 3) << 1) | gFragLo;
        int dl = gDlHi | (row & 15);
        uint2v z2; z2.x = 0u; z2.y = 0u;
        *(uint2v*)&slice[gc * 4096 + frag * 512 + (((dl << 3) | gW) ^ gSwz)] = z2;
      }
      if (e < eE) {
        int curDl = -1, cnt = 0;
        f32x4 accR; accR.x = accR.y = accR.z = accR.w = 0.f;
        ushort4 fvA[8], fvB[8];
        LDFV8(fvA, pkA);                 // pk banks prefetched earlier
        LDFV8(fvB, pkB);
#pragma unroll 1
        for (int eo = e; eo < eE; eo += 16) {
          PROC8(pkA, fvA, eo);                   // consume A (oldest, landed)
          LDPK8(pkA, eo + 16); LDFV8(fvA, pkA);  // refill A (clamped, uncond)
          PROC8(pkB, fvB, eo + 8);               // consume B
          LDPK8(pkB, eo + 24); LDFV8(fvB, pkB);  // refill B (clamped, uncond)
        }
        if (curDl >= 0) FLUSHROW();
      }
    } else {
      // self slice: raw copy of this tile's own features (rows owned by wave)
#pragma unroll
      for (int bi = 0; bi < 8; bi++) {
        int row = wid * 8 + bi;
        const uint2v vv = *(const uint2v*)&src[(size_t)(m0 + row) * F + lane * 4];
        int frag = (((row >> 4) & 3) << 1) | gFragLo;
        int dl = gDlHi | (row & 15);
        *(uint2v*)&slice[gc * 4096 + frag * 512 + (((dl << 3) | gW) ^ gSwz)] = vv;
      }
    }
    __syncthreads();
    // ---- prefetch next relation's id banks (hides under MFMA + barrier) ----
    if (r + 1 < 8) {
      BOUNDS(r + 1);
      LDPK8(pkA, e); LDPK8(pkB, e + 8);
    }
    // ---- phase 2: MFMA slice x Wt chunks kt = r*4 .. r*4+3 ----
#pragma unroll
    for (int c = 0; c < 4; c++) {
      const unsigned short* bc = Bt + (size_t)(r * 4 + c) * TSZ;
#pragma unroll
      for (int kk = 0; kk < 2; kk++) {
        short8 bfr[NI], afr[4];
#pragma unroll
        for (int ni = 0; ni < NI; ni++) {
          int rB2 = (wn & 127) + ni * 16;
          int fB = ((rB2 >> 6) << 3) + (((rB2 >> 4) & 3) << 1) + kk;
          bfr[ni] = *(const short8*)(bc + fB * 512);
        }
#pragma unroll
        for (int mi = 0; mi < 4; mi++) {
          int fA = (mi << 1) + kk;
          afr[mi] = *(const short8*)&slice[c * 4096 + fA * 512 + roff];
        }
#pragma unroll
        for (int mi = 0; mi < 4; mi++)
#pragma unroll
          for (int ni = 0; ni < NI; ni++)
            acc[mi][ni] = __builtin_amdgcn_mfma_f32_16x16x32_bf16(
                afr[mi], bfr[ni], acc[mi][ni], 0, 0, 0);
      }
    }
    __syncthreads();   // before overwriting the slice with the next relation
  }
#undef LDPK8
#undef LDFV8
#undef FLUSHROW
#undef PROC
#undef PROC8
#undef BOUNDS

  // ---- epilogue: bias (+relu) and store; output width = NI*128 ----
  const int Nld = NI * 128;
#pragma unroll
  for (int mi = 0; mi < 4; mi++) {
#pragma unroll
    for (int ni = 0; ni < NI; ni++) {
      int n = wn + ni * 16 + c15;
      float bv = bias[n];
#pragma unroll
      for (int rr = 0; rr < 4; rr++) {
        int m = m0 + mi * 16 + quad * 4 + rr;
        if (m < Nn) {
          float v = acc[mi][ni][rr] + bv;
          if (RELU) v = v > 0.f ? v : 0.f;
          if (OUTBF16) ((unsigned short*)outp)[(size_t)m * Nld + n] = f2bf(v);
          else         ((float*)outp)[(size_t)m * Nld + n] = v;
        }
      }
    }
  }
}

extern "C" void kernel_launch(void* const* d_in, const int* in_sizes, int n_in,
                              void* d_out, int out_size, void* d_ws, size_t ws_size,
                              hipStream_t stream) {
  const float* x     = (const float*)d_in[0];
  const int*   ei    = (const int*)d_in[1];   // [2, E]: src row then dst row
  const int*   et    = (const int*)d_in[2];   // [E]
  const float* W1    = (const float*)d_in[3]; // [2048,256]
  const float* root1 = (const float*)d_in[4]; // [256,256]
  const float* b1    = (const float*)d_in[5];
  const float* W2    = (const float*)d_in[6]; // [2048,128]
  const float* root2 = (const float*)d_in[7]; // [256,128]
  const float* b2    = (const float*)d_in[8];

  const int N = in_sizes[0] / F;              // 50000
  const int E = in_sizes[2];                  // 800000
  const int nbins = N * RELS;                 // 400000
  const int Mpad = ((N + 63) / 64) * 64;      // 50048 (div by 64)
  const int nsb = (nbins + SCAN_CHUNK - 1) / SCAN_CHUNK;

  char* base = (char*)d_ws;
  size_t off = 0;
  auto alloc = [&](size_t bytes) {
    void* r = base + off;
    off = (off + bytes + 511) & ~(size_t)511;
    return r;
  };
  unsigned short* Wt1  = (unsigned short*)alloc((size_t)2 * NKT * TSZ * 2);  // 256 cols
  unsigned short* Wt2  = (unsigned short*)alloc((size_t)1 * NKT * TSZ * 2);  // 128 cols
  int*            cnt  = (int*)alloc((size_t)2 * nbins * 4);  // [cnt | cursor]
  int*            strt = (int*)alloc((size_t)(nbins + 1) * 4);
  int*            bsum = (int*)alloc((size_t)(nsb + 1) * 4);
  unsigned int*   ssr2 = (unsigned int*)alloc((size_t)E * 4);
  unsigned short* xb   = (unsigned short*)alloc((size_t)Mpad * F * 2);  // bf16 x
  unsigned short* h    = (unsigned short*)alloc((size_t)Mpad * F * 2);  // bf16 h
  int* cur = cnt + nbins;
  (void)ws_size; (void)n_in; (void)out_size;

  hipMemsetAsync(cnt, 0, (size_t)2 * nbins * 4, stream);  // counts + cursor
  k_xb<<<(N * 64 + 255) / 256, 256, 0, stream>>>(x, xb, N);
  k_wt<<<(256 * KDIM + 255) / 256, 256, 0, stream>>>(W1, root1, Wt1, 256);
  k_wt<<<(128 * KDIM + 255) / 256, 256, 0, stream>>>(W2, root2, Wt2, 128);
  k_count<<<(E + 255) / 256, 256, 0, stream>>>(ei, et, cnt, E, N);
  k_scan1<<<nsb, 256, 0, stream>>>(cnt, strt, bsum, nbins);
  k_scan2<<<1, 1024, 0, stream>>>(bsum, nsb);
  k_scan3<<<(nbins + 255) / 256, 256, 0, stream>>>(strt, bsum, nbins, nsb);
  k_scatter<<<(E + 255) / 256, 256, 0, stream>>>(ei, et, strt, cur, ssr2, E, N);

  // Layer 1: stream-gather x (bf16, L3-resident) -> h. No A materialization.
  k_fused<2, true, true><<<Mpad / 64, 512, 0, stream>>>(xb, Wt1, strt, ssr2, b1, h, N);
  // Layer 2: stream-gather h -> output (fp32).
  k_fused<1, false, false><<<Mpad / 64, 512, 0, stream>>>(h, Wt2, strt, ssr2, b2, d_out, N);
}

// Round 11
// 634.789 us; speedup vs baseline: 1.1209x; 1.1209x over previous
//
#include <hip/hip_runtime.h>
#include <stdint.h>

#define RELS 8
#define F 256
#define KDIM 2304        // 8*256 stacked relations + 256 root/self columns
#define NKT 36           // KDIM / 64 k-tiles
#define TSZ 8192         // shorts per Wt (tile,kt) chunk: 128 rows x 64 cols
#define SCAN_CHUNK 1024  // bins per scan1 block (256 threads x 4)

// CSR bin order is RELATION-MAJOR: bin = rel*N + dst. For a fixed relation,
// the edges of any contiguous dst-row range are CONTIGUOUS in ssrc2 -> the
// fused kernel's gather is a sequential stream.
// FROZEN round-9 spill-free recipe: all gather-bank register writes are
// unconditional with CLAMPED indices; validity only at PROC via wave-uniform
// compare. Round 11 (round 9 geometry + three additive fixes):
//   (1) 3 banks (24-deep): ~800cyc refill hides under ~640cyc of processing.
//   (2) next relation's CSR bounds + pk banks prefetched under MFMA(r).
//   (3) slice double-buffer (2x32KB) -> ONE barrier per relation (build(r+2)
//       can't start until barrier(r+1), which slow waves pass only after
//       MFMA(r) -- so dropping the post-MFMA barrier is race-free).
// ssrc2 entry: src_id (bits 0..19) | (dst & 63) << 20.
//
// Wt global layout: tiled + FRAGMENT-MAJOR (round-4 verified). chunk(tile,kt)
// is contiguous 16KB holding rows [0,128) x k-units [0,8) (unit = 8 shorts):
//   frag = (row>>6)*8 + ((row>>4)&3)*2 + (unit>>2)
//   lane = (unit&3)*16 + (row&15)
//   addr = chunk_base + frag*512 + lane*8 + (k&7)       // shorts
// k_fused's 64-row LDS A-slice uses the same mapping (row>>6 = 0) with the
// round-6-verified dl-group XOR swizzle on write and read.

typedef __attribute__((ext_vector_type(8))) short short8;
typedef __attribute__((ext_vector_type(4))) float f32x4;
typedef __attribute__((ext_vector_type(2))) unsigned int uint2v;

__device__ __forceinline__ unsigned short f2bf(float f) {
  union { float f; unsigned int u; } v; v.f = f;
  unsigned int u = v.u;
  if ((u & 0x7f800000u) == 0x7f800000u) return (unsigned short)(u >> 16);
  return (unsigned short)((u + 0x7fffu + ((u >> 16) & 1u)) >> 16);  // RNE
}
__device__ __forceinline__ float bf2f(unsigned short b) {
  union { unsigned int u; float f; } v; v.u = ((unsigned int)b) << 16; return v.f;
}

// ---- x fp32 -> compact bf16 [N,256] (small L3-resident gather source)
__global__ void k_xb(const float* __restrict__ x, unsigned short* __restrict__ xb, int N) {
  int tid = blockIdx.x * blockDim.x + threadIdx.x;
  int n = tid >> 6, q = tid & 63;
  if (n >= N) return;
  const float4 v = *(const float4*)&x[(size_t)n * F + q * 4];
  ushort4 o;
  o.x = f2bf(v.x); o.y = f2bf(v.y); o.z = f2bf(v.z); o.w = f2bf(v.w);
  *(ushort4*)&xb[(size_t)n * F + q * 4] = o;
}

// ---- weight convert+transpose into tiled+fragment-major layout ----
// Wt content: row n (output col), k<2048: W[k][n]; else root[k-2048][n].
__global__ void k_wt(const float* __restrict__ W, const float* __restrict__ root,
                     unsigned short* __restrict__ Wt, int Ncols) {
  int tid = blockIdx.x * blockDim.x + threadIdx.x;
  int total = Ncols * KDIM;
  if (tid >= total) return;
  int n = tid / KDIM, k = tid - n * KDIM;
  float v = (k < 2048) ? W[(size_t)k * Ncols + n] : root[(size_t)(k - 2048) * Ncols + n];
  int tile = n >> 7, row = n & 127;
  int kt = k >> 6, c = k & 63;
  int u = c >> 3, w = c & 7;
  int frag = ((row >> 6) << 3) + (((row >> 4) & 3) << 1) + (u >> 2);
  int dl = ((u & 3) << 4) + (row & 15);
  Wt[(size_t)(tile * NKT + kt) * TSZ + frag * 512 + dl * 8 + w] = f2bf(v);
}

// ---- CSR build (relation-major bins) ----
__global__ void k_count(const int* __restrict__ ei, const int* __restrict__ et,
                        int* __restrict__ cnt, int E, int N) {
  int e = blockIdx.x * blockDim.x + threadIdx.x;
  if (e >= E) return;
  int bin = et[e] * N + ei[E + e];
  atomicAdd(&cnt[bin], 1);
}

__global__ void k_scan1(const int* __restrict__ cnt, int* __restrict__ start,
                        int* __restrict__ bsum, int nb) {
  __shared__ int tsum[256];
  const int t = threadIdx.x;
  const int idx = blockIdx.x * SCAN_CHUNK + t * 4;
  int v[4]; int s = 0;
#pragma unroll
  for (int i = 0; i < 4; i++) { v[i] = (idx + i < nb) ? cnt[idx + i] : 0; s += v[i]; }
  tsum[t] = s;
  __syncthreads();
  for (int d = 1; d < 256; d <<= 1) {
    int a = (t >= d) ? tsum[t - d] : 0;
    __syncthreads();
    tsum[t] += a;
    __syncthreads();
  }
  int ex = (t > 0) ? tsum[t - 1] : 0;
#pragma unroll
  for (int i = 0; i < 4; i++) { if (idx + i < nb) start[idx + i] = ex; ex += v[i]; }
  if (t == 255) bsum[blockIdx.x] = tsum[255];
}

__global__ void k_scan2(int* __restrict__ bsum, int nblocks) {
  __shared__ int sh[1024];
  const int t = threadIdx.x;
  sh[t] = (t < nblocks) ? bsum[t] : 0;
  __syncthreads();
  for (int d = 1; d < 1024; d <<= 1) {
    int a = (t >= d) ? sh[t - d] : 0;
    __syncthreads();
    sh[t] += a;
    __syncthreads();
  }
  if (t < nblocks) bsum[t] = (t > 0) ? sh[t - 1] : 0;
  if (t == 1023) bsum[nblocks] = sh[1023];
}

__global__ void k_scan3(int* __restrict__ start, const int* __restrict__ bsum,
                        int nb, int nblocks) {
  int i = blockIdx.x * blockDim.x + threadIdx.x;
  if (i < nb) start[i] += bsum[i >> 10];
  if (i == 0) start[nb] = bsum[nblocks];
}

__global__ void k_scatter(const int* __restrict__ ei, const int* __restrict__ et,
                          const int* __restrict__ start, int* __restrict__ cur,
                          unsigned int* __restrict__ ssrc2, int E, int N) {
  int e = blockIdx.x * blockDim.x + threadIdx.x;
  if (e >= E) return;
  int dst = ei[E + e];
  int bin = et[e] * N + dst;
  int p = atomicAdd(&cur[bin], 1);
  ssrc2[start[bin] + p] = (unsigned)ei[e] | ((unsigned)(dst & 63) << 20);
}

// ---- FUSED per-tile kernel: streaming aggregate -> LDS slice -> MFMA ----
// 4 waves x 16 rows/relation (round-9 geometry); relation-major bins make
// each wave's edges ONE contiguous ssrc2 range (mean ~32 edges), streamed
// via a 3-bank rotation (24 loads in flight; all register writes
// unconditional, clamped indices). Next relation's bounds + pk banks are
// prefetched under the MFMA phase. The slice is double-buffered so there is
// only ONE barrier per relation. Rows arrive in ascending order; a
// row-change flush writes the finished row into the fragment-major
// XOR-swizzled slice. Zero-fill is wave-ownership-partitioned.
// Accumulator spans all 9 relation slices; per-bin edge order == rounds 0-10.
template<int NI, bool RELU, bool OUTBF16>
__global__ __launch_bounds__(256, 2) void k_fused(
    const unsigned short* __restrict__ src, const unsigned short* __restrict__ Wt,
    const int* __restrict__ start, const unsigned int* __restrict__ ssrc2,
    const float* __restrict__ bias, void* __restrict__ outp, int Nn) {
  __shared__ unsigned short slice[2][4 * 4096];  // 2 x 32 KB double buffer
  const int t = threadIdx.x;
  const int lane = t & 63, wid = t >> 6;       // 4 waves, 16 rows each
  const int m0 = blockIdx.x * 64;
  const int c15 = lane & 15, quad = lane >> 4;
  const int wn = wid * (NI * 16);              // wave's output column base
  // gather constants: lane covers feature cols [4*lane, 4*lane+4)
  const int gc = lane >> 4;                    // k-chunk within slice
  const int gL = lane & 15;
  const int gFragLo = gL >> 3;
  const int gDlHi = ((gL >> 1) & 3) << 4;
  const int gW = (gL & 1) * 4;
  const int gSwz = ((gL >> 1) & 3) << 4;       // XOR key (shorts)

  f32x4 acc[4][NI];
#pragma unroll
  for (int i = 0; i < 4; i++)
#pragma unroll
    for (int j = 0; j < NI; j++) acc[i][j] = (f32x4)0.f;

  const unsigned short* Bt = Wt + (size_t)(wn >> 7) * NKT * TSZ + lane * 8;
  const int roff = (lane << 3) ^ ((lane >> 4 & 3) << 4);  // swizzled frag read

// unconditional, index-clamped loads: every register written on every path.
#define LDPK8(P_, eo_)                                                       \
  { _Pragma("unroll") for (int j = 0; j < 8; j++) {                          \
      int i_ = (eo_) + j; P_[j] = ssrc2[i_ < eEm1 ? i_ : eEm1]; } }
#define LDFV8(Fv_, P_)                                                       \
  { _Pragma("unroll") for (int j = 0; j < 8; j++)                            \
      Fv_[j] = *(const ushort4*)&src[(size_t)(P_[j] & 0xFFFFFu) * F + lane * 4]; }
#define FLUSHROW()                                                           \
  {                                                                          \
    float s_ = 1.0f / (float)(cnt > 1 ? cnt : 1);                            \
    int frag_ = (((curDl >> 4) & 3) << 1) | gFragLo;                         \
    int dloc_ = gDlHi | (curDl & 15);                                        \
    uint2v o_;                                                               \
    o_.x = (unsigned)f2bf(accR.x * s_) | ((unsigned)f2bf(accR.y * s_) << 16);\
    o_.y = (unsigned)f2bf(accR.z * s_) | ((unsigned)f2bf(accR.w * s_) << 16);\
    *(uint2v*)&sl[gc * 4096 + frag_ * 512 + (((dloc_ << 3) | gW) ^ gSwz)] = o_; \
  }
#define PROC(pk_, fv_)                                                       \
  {                                                                          \
    int dl_ = (int)((pk_) >> 20);                                            \
    if (dl_ != curDl) {                                                      \
      if (curDl >= 0) FLUSHROW();                                            \
      curDl = dl_; cnt = 0;                                                  \
      accR.x = 0.f; accR.y = 0.f; accR.z = 0.f; accR.w = 0.f;                \
    }                                                                        \
    accR.x += bf2f((fv_).x); accR.y += bf2f((fv_).y);                        \
    accR.z += bf2f((fv_).z); accR.w += bf2f((fv_).w);                        \
    cnt++;                                                                   \
  }
#define PROC8(P_, Fv_, base_)                                                \
  { _Pragma("unroll") for (int j = 0; j < 8; j++)                            \
      if ((base_) + j < eE) PROC(P_[j], Fv_[j]); }
#define BOUNDS(r_)                                                           \
  {                                                                          \
    int rA_ = m0 + wid * 16;                                                 \
    int rB_ = rA_ + 16;                                                      \
    rA_ = rA_ < Nn ? rA_ : Nn;                                               \
    rB_ = rB_ < Nn ? rB_ : Nn;                                               \
    e = start[(r_) * Nn + rA_];                                              \
    eE = start[(r_) * Nn + rB_];                                             \
    eEm1 = (eE > e) ? eE - 1 : 0;                                            \
  }

  int e, eE, eEm1;
  unsigned pkA[8], pkB[8], pkC[8];
  BOUNDS(0);
  LDPK8(pkA, e); LDPK8(pkB, e + 8); LDPK8(pkC, e + 16);  // rel-0 ids in flight

  for (int r = 0; r < 9; r++) {
    unsigned short* sl = slice[r & 1];
    // ---- phase 1: build fragment-major A-slice for relation r in LDS ----
    if (r < 8) {
      // zero-fill ONLY this wave's frags {2wid, 2wid+1} in all 4 chunks
      short8 z8 = {0, 0, 0, 0, 0, 0, 0, 0};
#pragma unroll
      for (int z = 0; z < 8; z++)
        *(short8*)&sl[(z >> 1) * 4096 + (wid * 2 + (z & 1)) * 512 + lane * 8] = z8;

      if (e < eE) {
        int curDl = -1, cnt = 0;
        f32x4 accR; accR.x = accR.y = accR.z = accR.w = 0.f;
        ushort4 fvA[8], fvB[8], fvC[8];
        LDFV8(fvA, pkA);                 // pk banks prefetched under MFMA(r-1)
        LDFV8(fvB, pkB);
        LDFV8(fvC, pkC);
#pragma unroll 1
        for (int eo = e; eo < eE; eo += 24) {
          PROC8(pkA, fvA, eo);                   // consume A (oldest, landed)
          LDPK8(pkA, eo + 24); LDFV8(fvA, pkA);  // refill A (clamped, uncond)
          PROC8(pkB, fvB, eo + 8);               // consume B
          LDPK8(pkB, eo + 32); LDFV8(fvB, pkB);  // refill B
          PROC8(pkC, fvC, eo + 16);              // consume C
          LDPK8(pkC, eo + 40); LDFV8(fvC, pkC);  // refill C
        }
        if (curDl >= 0) FLUSHROW();
      }
    } else {
      // self slice: raw copy of this tile's own features (rows owned by wave)
#pragma unroll 4
      for (int bi = 0; bi < 16; bi++) {
        int row = (wid << 4) + bi;
        const uint2v vv = *(const uint2v*)&src[(size_t)(m0 + row) * F + lane * 4];
        int frag = (((row >> 4) & 3) << 1) | gFragLo;
        int dl = gDlHi | (row & 15);
        *(uint2v*)&sl[gc * 4096 + frag * 512 + (((dl << 3) | gW) ^ gSwz)] = vv;
      }
    }
    __syncthreads();   // slice[r&1] complete; build(r+1) targets slice[~r&1]
    // ---- prefetch next relation's bounds + id banks (hide under MFMA) ----
    if (r + 1 < 8) {
      BOUNDS(r + 1);
      LDPK8(pkA, e); LDPK8(pkB, e + 8); LDPK8(pkC, e + 16);
    }
    // ---- phase 2: MFMA slice x Wt chunks kt = r*4 .. r*4+3 ----
#pragma unroll
    for (int c = 0; c < 4; c++) {
      const unsigned short* bc = Bt + (size_t)(r * 4 + c) * TSZ;
#pragma unroll
      for (int kk = 0; kk < 2; kk++) {
        short8 bfr[NI], afr[4];
#pragma unroll
        for (int ni = 0; ni < NI; ni++) {
          int rB2 = (wn & 127) + ni * 16;
          int fB = ((rB2 >> 6) << 3) + (((rB2 >> 4) & 3) << 1) + kk;
          bfr[ni] = *(const short8*)(bc + fB * 512);
        }
#pragma unroll
        for (int mi = 0; mi < 4; mi++) {
          int fA = (mi << 1) + kk;
          afr[mi] = *(const short8*)&sl[c * 4096 + fA * 512 + roff];
        }
#pragma unroll
        for (int mi = 0; mi < 4; mi++)
#pragma unroll
          for (int ni = 0; ni < NI; ni++)
            acc[mi][ni] = __builtin_amdgcn_mfma_f32_16x16x32_bf16(
                afr[mi], bfr[ni], acc[mi][ni], 0, 0, 0);
      }
    }
    // no trailing barrier: next build writes the OTHER slice buffer, and
    // build(r+2) into THIS buffer is fenced by barrier(r+1).
  }
#undef LDPK8
#undef LDFV8
#undef FLUSHROW
#undef PROC
#undef PROC8
#undef BOUNDS

  // ---- epilogue: bias (+relu) and store; output width = NI*64 ----
  const int Nld = NI * 64;
#pragma unroll
  for (int mi = 0; mi < 4; mi++) {
#pragma unroll
    for (int ni = 0; ni < NI; ni++) {
      int n = wn + ni * 16 + c15;
      float bv = bias[n];
#pragma unroll
      for (int rr = 0; rr < 4; rr++) {
        int m = m0 + mi * 16 + quad * 4 + rr;
        if (m < Nn) {
          float v = acc[mi][ni][rr] + bv;
          if (RELU) v = v > 0.f ? v : 0.f;
          if (OUTBF16) ((unsigned short*)outp)[(size_t)m * Nld + n] = f2bf(v);
          else         ((float*)outp)[(size_t)m * Nld + n] = v;
        }
      }
    }
  }
}

extern "C" void kernel_launch(void* const* d_in, const int* in_sizes, int n_in,
                              void* d_out, int out_size, void* d_ws, size_t ws_size,
                              hipStream_t stream) {
  const float* x     = (const float*)d_in[0];
  const int*   ei    = (const int*)d_in[1];   // [2, E]: src row then dst row
  const int*   et    = (const int*)d_in[2];   // [E]
  const float* W1    = (const float*)d_in[3]; // [2048,256]
  const float* root1 = (const float*)d_in[4]; // [256,256]
  const float* b1    = (const float*)d_in[5];
  const float* W2    = (const float*)d_in[6]; // [2048,128]
  const float* root2 = (const float*)d_in[7]; // [256,128]
  const float* b2    = (const float*)d_in[8];

  const int N = in_sizes[0] / F;              // 50000
  const int E = in_sizes[2];                  // 800000
  const int nbins = N * RELS;                 // 400000
  const int Mpad = ((N + 63) / 64) * 64;      // 50048 (div by 64)
  const int nsb = (nbins + SCAN_CHUNK - 1) / SCAN_CHUNK;

  char* base = (char*)d_ws;
  size_t off = 0;
  auto alloc = [&](size_t bytes) {
    void* r = base + off;
    off = (off + bytes + 511) & ~(size_t)511;
    return r;
  };
  unsigned short* Wt1  = (unsigned short*)alloc((size_t)2 * NKT * TSZ * 2);  // 256 cols
  unsigned short* Wt2  = (unsigned short*)alloc((size_t)1 * NKT * TSZ * 2);  // 128 cols
  int*            cnt  = (int*)alloc((size_t)2 * nbins * 4);  // [cnt | cursor]
  int*            strt = (int*)alloc((size_t)(nbins + 1) * 4);
  int*            bsum = (int*)alloc((size_t)(nsb + 1) * 4);
  unsigned int*   ssr2 = (unsigned int*)alloc((size_t)E * 4);
  unsigned short* xb   = (unsigned short*)alloc((size_t)Mpad * F * 2);  // bf16 x
  unsigned short* h    = (unsigned short*)alloc((size_t)Mpad * F * 2);  // bf16 h
  int* cur = cnt + nbins;
  (void)ws_size; (void)n_in; (void)out_size;

  hipMemsetAsync(cnt, 0, (size_t)2 * nbins * 4, stream);  // counts + cursor
  k_xb<<<(N * 64 + 255) / 256, 256, 0, stream>>>(x, xb, N);
  k_wt<<<(256 * KDIM + 255) / 256, 256, 0, stream>>>(W1, root1, Wt1, 256);
  k_wt<<<(128 * KDIM + 255) / 256, 256, 0, stream>>>(W2, root2, Wt2, 128);
  k_count<<<(E + 255) / 256, 256, 0, stream>>>(ei, et, cnt, E, N);
  k_scan1<<<nsb, 256, 0, stream>>>(cnt, strt, bsum, nbins);
  k_scan2<<<1, 1024, 0, stream>>>(bsum, nsb);
  k_scan3<<<(nbins + 255) / 256, 256, 0, stream>>>(strt, bsum, nbins, nsb);
  k_scatter<<<(E + 255) / 256, 256, 0, stream>>>(ei, et, strt, cur, ssr2, E, N);

  // Layer 1: stream-gather x (bf16, L3-resident) -> h. No A materialization.
  k_fused<4, true, true><<<Mpad / 64, 256, 0, stream>>>(xb, Wt1, strt, ssr2, b1, h, N);
  // Layer 2: stream-gather h -> output (fp32).
  k_fused<2, false, false><<<Mpad / 64, 256, 0, stream>>>(h, Wt2, strt, ssr2, b2, d_out, N);
}

// Round 12
// 506.196 us; speedup vs baseline: 1.4057x; 1.2540x over previous
//
#include <hip/hip_runtime.h>
#include <stdint.h>

#define RELS 8
#define F 256
#define KDIM 2304        // 8*256 stacked relations + 256 root/self columns
#define NKT 36           // KDIM / 64 k-tiles
#define TSZ 8192         // shorts per Wt (tile,kt) chunk: 128 rows x 64 cols
#define SCAN_CHUNK 1024  // bins per scan1 block (256 threads x 4)

// CSR bin order is RELATION-MAJOR: bin = rel*N + dst. For a fixed relation,
// the edges of any contiguous dst-row range are CONTIGUOUS in ssrc2 -> the
// fused kernel's gather is a sequential stream (round-7 insight).
// FROZEN round-9 spill-free recipe: all gather-bank register writes are
// unconditional with CLAMPED indices; validity only at PROC via wave-uniform
// compare (rounds 7/8 lost 150-500MB to scratch without this).
// Round 12: RELATION-SPLIT. Rounds 9-11 were grid-limited (782 blocks =
// 3 blocks/CU of total work -> ~6.4 waves/CU; LDS/VGPR would allow ~20).
// Each 64-row tile is now TWO blocks: y=0 does relations 0-3, y=1 does
// relations 4-7 + self. Each stores its fp32 partial accumulator; k_comb
// does out = act(p0 + p1 + bias). Per-bin gather order unchanged; only the
// fp32 (sum r<4)+(sum r>=4) associativity differs (~1e-6 relative).
// ssrc2 entry: src_id (bits 0..19) | (dst & 63) << 20.
//
// Wt global layout: tiled + FRAGMENT-MAJOR (round-4 verified). chunk(tile,kt)
// is contiguous 16KB holding rows [0,128) x k-units [0,8) (unit = 8 shorts):
//   frag = (row>>6)*8 + ((row>>4)&3)*2 + (unit>>2)
//   lane = (unit&3)*16 + (row&15)
//   addr = chunk_base + frag*512 + lane*8 + (k&7)       // shorts
// k_fused's 64-row LDS A-slice uses the same mapping (row>>6 = 0) with the
// round-6-verified dl-group XOR swizzle on write and read.

typedef __attribute__((ext_vector_type(8))) short short8;
typedef __attribute__((ext_vector_type(4))) float f32x4;
typedef __attribute__((ext_vector_type(2))) unsigned int uint2v;

__device__ __forceinline__ unsigned short f2bf(float f) {
  union { float f; unsigned int u; } v; v.f = f;
  unsigned int u = v.u;
  if ((u & 0x7f800000u) == 0x7f800000u) return (unsigned short)(u >> 16);
  return (unsigned short)((u + 0x7fffu + ((u >> 16) & 1u)) >> 16);  // RNE
}
__device__ __forceinline__ float bf2f(unsigned short b) {
  union { unsigned int u; float f; } v; v.u = ((unsigned int)b) << 16; return v.f;
}

// ---- x fp32 -> compact bf16 [N,256] (small L3-resident gather source)
__global__ void k_xb(const float* __restrict__ x, unsigned short* __restrict__ xb, int N) {
  int tid = blockIdx.x * blockDim.x + threadIdx.x;
  int n = tid >> 6, q = tid & 63;
  if (n >= N) return;
  const float4 v = *(const float4*)&x[(size_t)n * F + q * 4];
  ushort4 o;
  o.x = f2bf(v.x); o.y = f2bf(v.y); o.z = f2bf(v.z); o.w = f2bf(v.w);
  *(ushort4*)&xb[(size_t)n * F + q * 4] = o;
}

// ---- weight convert+transpose into tiled+fragment-major layout ----
// Wt content: row n (output col), k<2048: W[k][n]; else root[k-2048][n].
__global__ void k_wt(const float* __restrict__ W, const float* __restrict__ root,
                     unsigned short* __restrict__ Wt, int Ncols) {
  int tid = blockIdx.x * blockDim.x + threadIdx.x;
  int total = Ncols * KDIM;
  if (tid >= total) return;
  int n = tid / KDIM, k = tid - n * KDIM;
  float v = (k < 2048) ? W[(size_t)k * Ncols + n] : root[(size_t)(k - 2048) * Ncols + n];
  int tile = n >> 7, row = n & 127;
  int kt = k >> 6, c = k & 63;
  int u = c >> 3, w = c & 7;
  int frag = ((row >> 6) << 3) + (((row >> 4) & 3) << 1) + (u >> 2);
  int dl = ((u & 3) << 4) + (row & 15);
  Wt[(size_t)(tile * NKT + kt) * TSZ + frag * 512 + dl * 8 + w] = f2bf(v);
}

// ---- CSR build (relation-major bins) ----
__global__ void k_count(const int* __restrict__ ei, const int* __restrict__ et,
                        int* __restrict__ cnt, int E, int N) {
  int e = blockIdx.x * blockDim.x + threadIdx.x;
  if (e >= E) return;
  int bin = et[e] * N + ei[E + e];
  atomicAdd(&cnt[bin], 1);
}

__global__ void k_scan1(const int* __restrict__ cnt, int* __restrict__ start,
                        int* __restrict__ bsum, int nb) {
  __shared__ int tsum[256];
  const int t = threadIdx.x;
  const int idx = blockIdx.x * SCAN_CHUNK + t * 4;
  int v[4]; int s = 0;
#pragma unroll
  for (int i = 0; i < 4; i++) { v[i] = (idx + i < nb) ? cnt[idx + i] : 0; s += v[i]; }
  tsum[t] = s;
  __syncthreads();
  for (int d = 1; d < 256; d <<= 1) {
    int a = (t >= d) ? tsum[t - d] : 0;
    __syncthreads();
    tsum[t] += a;
    __syncthreads();
  }
  int ex = (t > 0) ? tsum[t - 1] : 0;
#pragma unroll
  for (int i = 0; i < 4; i++) { if (idx + i < nb) start[idx + i] = ex; ex += v[i]; }
  if (t == 255) bsum[blockIdx.x] = tsum[255];
}

__global__ void k_scan2(int* __restrict__ bsum, int nblocks) {
  __shared__ int sh[1024];
  const int t = threadIdx.x;
  sh[t] = (t < nblocks) ? bsum[t] : 0;
  __syncthreads();
  for (int d = 1; d < 1024; d <<= 1) {
    int a = (t >= d) ? sh[t - d] : 0;
    __syncthreads();
    sh[t] += a;
    __syncthreads();
  }
  if (t < nblocks) bsum[t] = (t > 0) ? sh[t - 1] : 0;
  if (t == 1023) bsum[nblocks] = sh[1023];
}

__global__ void k_scan3(int* __restrict__ start, const int* __restrict__ bsum,
                        int nb, int nblocks) {
  int i = blockIdx.x * blockDim.x + threadIdx.x;
  if (i < nb) start[i] += bsum[i >> 10];
  if (i == 0) start[nb] = bsum[nblocks];
}

__global__ void k_scatter(const int* __restrict__ ei, const int* __restrict__ et,
                          const int* __restrict__ start, int* __restrict__ cur,
                          unsigned int* __restrict__ ssrc2, int E, int N) {
  int e = blockIdx.x * blockDim.x + threadIdx.x;
  if (e >= E) return;
  int dst = ei[E + e];
  int bin = et[e] * N + dst;
  int p = atomicAdd(&cur[bin], 1);
  ssrc2[start[bin] + p] = (unsigned)ei[e] | ((unsigned)(dst & 63) << 20);
}

// ---- FUSED per-tile kernel: streaming aggregate -> LDS slice -> MFMA ----
// Round-9 body, relation-split across blockIdx.y (y=0: rel 0-3; y=1: rel
// 4-7 + self). 4 waves x 16 rows/relation; relation-major bins make each
// wave's edges ONE contiguous ssrc2 range, streamed via the round-9 2-bank
// double buffer (all register writes unconditional, clamped indices). Rows
// arrive in ascending order; a row-change flush writes the finished row into
// the fragment-major XOR-swizzled slice. Zero-fill is wave-ownership-
// partitioned. Partial accumulator stored fp32; k_comb adds halves + bias.
template<int NI>
__global__ __launch_bounds__(256, 2) void k_fused(
    const unsigned short* __restrict__ src, const unsigned short* __restrict__ Wt,
    const int* __restrict__ start, const unsigned int* __restrict__ ssrc2,
    float* __restrict__ pout0, float* __restrict__ pout1, int Nn) {
  __shared__ unsigned short slice[4 * 4096];   // 32 KB: [chunk][frag<8][512]
  const int t = threadIdx.x;
  const int lane = t & 63, wid = t >> 6;       // 4 waves, 16 rows each
  const int m0 = blockIdx.x * 64;
  const int half = blockIdx.y;                 // 0: rel 0-3; 1: rel 4-7 + self
  const int r0 = half ? 4 : 0;
  const int rEnd = half ? 9 : 4;
  float* __restrict__ pout = half ? pout1 : pout0;
  const int c15 = lane & 15, quad = lane >> 4;
  const int wn = wid * (NI * 16);              // wave's output column base
  // gather constants: lane covers feature cols [4*lane, 4*lane+4)
  const int gc = lane >> 4;                    // k-chunk within slice
  const int gL = lane & 15;
  const int gFragLo = gL >> 3;
  const int gDlHi = ((gL >> 1) & 3) << 4;
  const int gW = (gL & 1) * 4;
  const int gSwz = ((gL >> 1) & 3) << 4;       // XOR key (shorts)

  f32x4 acc[4][NI];
#pragma unroll
  for (int i = 0; i < 4; i++)
#pragma unroll
    for (int j = 0; j < NI; j++) acc[i][j] = (f32x4)0.f;

  const unsigned short* Bt = Wt + (size_t)(wn >> 7) * NKT * TSZ + lane * 8;
  const int roff = (lane << 3) ^ ((lane >> 4 & 3) << 4);  // swizzled frag read

// unconditional, index-clamped loads: every register written on every path.
#define LDPK8(P_, eo_)                                                       \
  { _Pragma("unroll") for (int j = 0; j < 8; j++) {                          \
      int i_ = (eo_) + j; P_[j] = ssrc2[i_ < eEm1 ? i_ : eEm1]; } }
#define LDFV8(Fv_, P_)                                                       \
  { _Pragma("unroll") for (int j = 0; j < 8; j++)                            \
      Fv_[j] = *(const ushort4*)&src[(size_t)(P_[j] & 0xFFFFFu) * F + lane * 4]; }
#define FLUSHROW()                                                           \
  {                                                                          \
    float s_ = 1.0f / (float)(cnt > 1 ? cnt : 1);                            \
    int frag_ = (((curDl >> 4) & 3) << 1) | gFragLo;                         \
    int dloc_ = gDlHi | (curDl & 15);                                        \
    uint2v o_;                                                               \
    o_.x = (unsigned)f2bf(accR.x * s_) | ((unsigned)f2bf(accR.y * s_) << 16);\
    o_.y = (unsigned)f2bf(accR.z * s_) | ((unsigned)f2bf(accR.w * s_) << 16);\
    *(uint2v*)&slice[gc * 4096 + frag_ * 512 + (((dloc_ << 3) | gW) ^ gSwz)] = o_; \
  }
#define PROC(pk_, fv_)                                                       \
  {                                                                          \
    int dl_ = (int)((pk_) >> 20);                                            \
    if (dl_ != curDl) {                                                      \
      if (curDl >= 0) FLUSHROW();                                            \
      curDl = dl_; cnt = 0;                                                  \
      accR.x = 0.f; accR.y = 0.f; accR.z = 0.f; accR.w = 0.f;                \
    }                                                                        \
    accR.x += bf2f((fv_).x); accR.y += bf2f((fv_).y);                        \
    accR.z += bf2f((fv_).z); accR.w += bf2f((fv_).w);                        \
    cnt++;                                                                   \
  }
#define PROC8(P_, Fv_, base_)                                                \
  { _Pragma("unroll") for (int j = 0; j < 8; j++)                            \
      if ((base_) + j < eE) PROC(P_[j], Fv_[j]); }

  for (int r = r0; r < rEnd; r++) {
    // ---- phase 1: build fragment-major A-slice for relation r in LDS ----
    if (r < 8) {
      // zero-fill ONLY this wave's frags {2wid, 2wid+1} in all 4 chunks
      short8 z8 = {0, 0, 0, 0, 0, 0, 0, 0};
#pragma unroll
      for (int z = 0; z < 8; z++)
        *(short8*)&slice[(z >> 1) * 4096 + (wid * 2 + (z & 1)) * 512 + lane * 8] = z8;

      int rA = m0 + wid * 16;
      int rB = rA + 16;
      rA = rA < Nn ? rA : Nn;
      rB = rB < Nn ? rB : Nn;
      int e = start[r * Nn + rA];
      const int eE = start[r * Nn + rB];

      if (e < eE) {
        const int eEm1 = eE - 1;
        int curDl = -1, cnt = 0;
        f32x4 accR; accR.x = accR.y = accR.z = accR.w = 0.f;

        unsigned pkA[8], pkB[8];
        ushort4 fvA[8], fvB[8];
        LDPK8(pkA, e);     LDFV8(fvA, pkA);
        LDPK8(pkB, e + 8); LDFV8(fvB, pkB);
#pragma unroll 1
        for (int eo = e; eo < eE; eo += 16) {
          PROC8(pkA, fvA, eo);                   // consume A (oldest, landed)
          LDPK8(pkA, eo + 16); LDFV8(fvA, pkA);  // refill A (clamped, uncond)
          PROC8(pkB, fvB, eo + 8);               // consume B
          LDPK8(pkB, eo + 24); LDFV8(fvB, pkB);  // refill B (clamped, uncond)
        }
        if (curDl >= 0) FLUSHROW();
      }
    } else {
      // self slice: raw copy of this tile's own features (rows owned by wave)
#pragma unroll 4
      for (int bi = 0; bi < 16; bi++) {
        int row = (wid << 4) + bi;
        const uint2v vv = *(const uint2v*)&src[(size_t)(m0 + row) * F + lane * 4];
        int frag = (((row >> 4) & 3) << 1) | gFragLo;
        int dl = gDlHi | (row & 15);
        *(uint2v*)&slice[gc * 4096 + frag * 512 + (((dl << 3) | gW) ^ gSwz)] = vv;
      }
    }
    __syncthreads();
    // ---- phase 2: MFMA slice x Wt chunks kt = r*4 .. r*4+3 ----
#pragma unroll
    for (int c = 0; c < 4; c++) {
      const unsigned short* bc = Bt + (size_t)(r * 4 + c) * TSZ;
#pragma unroll
      for (int kk = 0; kk < 2; kk++) {
        short8 bfr[NI], afr[4];
#pragma unroll
        for (int ni = 0; ni < NI; ni++) {
          int rB2 = (wn & 127) + ni * 16;
          int fB = ((rB2 >> 6) << 3) + (((rB2 >> 4) & 3) << 1) + kk;
          bfr[ni] = *(const short8*)(bc + fB * 512);
        }
#pragma unroll
        for (int mi = 0; mi < 4; mi++) {
          int fA = (mi << 1) + kk;
          afr[mi] = *(const short8*)&slice[c * 4096 + fA * 512 + roff];
        }
#pragma unroll
        for (int mi = 0; mi < 4; mi++)
#pragma unroll
          for (int ni = 0; ni < NI; ni++)
            acc[mi][ni] = __builtin_amdgcn_mfma_f32_16x16x32_bf16(
                afr[mi], bfr[ni], acc[mi][ni], 0, 0, 0);
      }
    }
    __syncthreads();   // before overwriting the slice with the next relation
  }
#undef LDPK8
#undef LDFV8
#undef FLUSHROW
#undef PROC
#undef PROC8

  // ---- epilogue: store fp32 partial (bias/act applied in k_comb) ----
  const int Nld = NI * 64;
#pragma unroll
  for (int mi = 0; mi < 4; mi++) {
#pragma unroll
    for (int ni = 0; ni < NI; ni++) {
      int n = wn + ni * 16 + c15;
#pragma unroll
      for (int rr = 0; rr < 4; rr++) {
        int m = m0 + mi * 16 + quad * 4 + rr;
        if (m < Nn) pout[(size_t)m * Nld + n] = acc[mi][ni][rr];
      }
    }
  }
}

// ---- combine partials: out = act(p0 + p1 + bias) ----
template<int C, bool RELU, bool OUTBF16>
__global__ void k_comb(const float* __restrict__ p0, const float* __restrict__ p1,
                       const float* __restrict__ bias, void* __restrict__ outp, int N) {
  int idx = blockIdx.x * blockDim.x + threadIdx.x;     // one float4 per thread
  if (idx >= N * (C / 4)) return;
  int c4 = idx & (C / 4 - 1);
  const float4 a = *(const float4*)&p0[(size_t)idx * 4];
  const float4 b = *(const float4*)&p1[(size_t)idx * 4];
  const float4 bv = *(const float4*)&bias[c4 * 4];
  float vx = a.x + b.x + bv.x, vy = a.y + b.y + bv.y;
  float vz = a.z + b.z + bv.z, vw = a.w + b.w + bv.w;
  if (RELU) {
    vx = vx > 0.f ? vx : 0.f; vy = vy > 0.f ? vy : 0.f;
    vz = vz > 0.f ? vz : 0.f; vw = vw > 0.f ? vw : 0.f;
  }
  if (OUTBF16) {
    ushort4 o; o.x = f2bf(vx); o.y = f2bf(vy); o.z = f2bf(vz); o.w = f2bf(vw);
    *(ushort4*)&((unsigned short*)outp)[(size_t)idx * 4] = o;
  } else {
    float4 v; v.x = vx; v.y = vy; v.z = vz; v.w = vw;
    *(float4*)&((float*)outp)[(size_t)idx * 4] = v;
  }
}

extern "C" void kernel_launch(void* const* d_in, const int* in_sizes, int n_in,
                              void* d_out, int out_size, void* d_ws, size_t ws_size,
                              hipStream_t stream) {
  const float* x     = (const float*)d_in[0];
  const int*   ei    = (const int*)d_in[1];   // [2, E]: src row then dst row
  const int*   et    = (const int*)d_in[2];   // [E]
  const float* W1    = (const float*)d_in[3]; // [2048,256]
  const float* root1 = (const float*)d_in[4]; // [256,256]
  const float* b1    = (const float*)d_in[5];
  const float* W2    = (const float*)d_in[6]; // [2048,128]
  const float* root2 = (const float*)d_in[7]; // [256,128]
  const float* b2    = (const float*)d_in[8];

  const int N = in_sizes[0] / F;              // 50000
  const int E = in_sizes[2];                  // 800000
  const int nbins = N * RELS;                 // 400000
  const int Mpad = ((N + 63) / 64) * 64;      // 50048 (div by 64)
  const int nsb = (nbins + SCAN_CHUNK - 1) / SCAN_CHUNK;

  char* base = (char*)d_ws;
  size_t off = 0;
  auto alloc = [&](size_t bytes) {
    void* r = base + off;
    off = (off + bytes + 511) & ~(size_t)511;
    return r;
  };
  unsigned short* Wt1  = (unsigned short*)alloc((size_t)2 * NKT * TSZ * 2);  // 256 cols
  unsigned short* Wt2  = (unsigned short*)alloc((size_t)1 * NKT * TSZ * 2);  // 128 cols
  int*            cnt  = (int*)alloc((size_t)2 * nbins * 4);  // [cnt | cursor]
  int*            strt = (int*)alloc((size_t)(nbins + 1) * 4);
  int*            bsum = (int*)alloc((size_t)(nsb + 1) * 4);
  unsigned int*   ssr2 = (unsigned int*)alloc((size_t)E * 4);
  unsigned short* xb   = (unsigned short*)alloc((size_t)Mpad * F * 2);  // bf16 x
  unsigned short* h    = (unsigned short*)alloc((size_t)Mpad * F * 2);  // bf16 h
  float*          p0   = (float*)alloc((size_t)Mpad * 256 * 4);  // fp32 partials
  float*          p1   = (float*)alloc((size_t)Mpad * 256 * 4);
  int* cur = cnt + nbins;
  (void)ws_size; (void)n_in; (void)out_size;

  hipMemsetAsync(cnt, 0, (size_t)2 * nbins * 4, stream);  // counts + cursor
  k_xb<<<(N * 64 + 255) / 256, 256, 0, stream>>>(x, xb, N);
  k_wt<<<(256 * KDIM + 255) / 256, 256, 0, stream>>>(W1, root1, Wt1, 256);
  k_wt<<<(128 * KDIM + 255) / 256, 256, 0, stream>>>(W2, root2, Wt2, 128);
  k_count<<<(E + 255) / 256, 256, 0, stream>>>(ei, et, cnt, E, N);
  k_scan1<<<nsb, 256, 0, stream>>>(cnt, strt, bsum, nbins);
  k_scan2<<<1, 1024, 0, stream>>>(bsum, nsb);
  k_scan3<<<(nbins + 255) / 256, 256, 0, stream>>>(strt, bsum, nbins, nsb);
  k_scatter<<<(E + 255) / 256, 256, 0, stream>>>(ei, et, strt, cur, ssr2, E, N);

  // Layer 1: relation-split fused gather+GEMM into fp32 partials, then
  // combine (+bias, relu, ->bf16 h). No A materialization.
  k_fused<4><<<dim3(Mpad / 64, 2), 256, 0, stream>>>(xb, Wt1, strt, ssr2, p0, p1, N);
  k_comb<256, true, true><<<(N * 64 + 255) / 256, 256, 0, stream>>>(p0, p1, b1, h, N);
  // Layer 2: same, partials reused; combine writes fp32 d_out.
  k_fused<2><<<dim3(Mpad / 64, 2), 256, 0, stream>>>(h, Wt2, strt, ssr2, p0, p1, N);
  k_comb<128, false, false><<<(N * 32 + 255) / 256, 256, 0, stream>>>(p0, p1, b2, d_out, N);
}